// Round 1
// baseline (964.632 us; speedup 1.0000x reference)
//
#include <hip/hip_runtime.h>

#define Bb   8
#define NPIX 16384
#define N0T  16384
#define N1T  4096
#define C0d  256
#define C1d  512

// ---------- pixel index (matches jnp.round = round-half-even via rintf) ----------
__device__ __forceinline__ int pix_idx(float lx, float ly, int HW) {
  lx = fminf(fmaxf(lx, -1.f), 1.f);
  ly = fminf(fmaxf(ly, -1.f), 1.f);
  float half = (float)HW * 0.5f;
  float fx = (lx + 1.0f) * half - 0.5f;   // power-of-2 scale: exact, fma-safe
  float fy = (ly + 1.0f) * half - 0.5f;
  int px = (int)rintf(fx);
  int py = (int)rintf(fy);
  px = min(max(px, 0), HW - 1);
  py = min(max(py, 0), HW - 1);
  return py * HW + px;
}

// ---------- token2map scatter: sum[b][pix][c] += x0[b][idx0[bp]][c]; cnt += 1 ----------
__global__ __launch_bounds__(256) void k_scatter_t2m(
    const float* __restrict__ x0, const int* __restrict__ idx0,
    const float* __restrict__ loc, float* __restrict__ sum, float* __restrict__ cnt) {
  int bp = blockIdx.x;          // b*NPIX + p
  int c  = threadIdx.x;         // 0..255
  int b  = bp >> 14;
  float lx = loc[2 * bp + 0];
  float ly = loc[2 * bp + 1];
  int pix = pix_idx(lx, ly, 128);
  int s = idx0[bp];             // [0, N0T)
  float v = x0[((size_t)b * N0T + s) * C0d + c];
  atomicAdd(&sum[((size_t)b * 16384 + pix) * C0d + c], v);
  if (c == 0) atomicAdd(&cnt[b * 16384 + pix], 1.0f);
}

// ---------- normalize + depthwise 3x3 stride2 pad1 -> xm2 [B][64*64][C0] (HWC) ----------
__global__ __launch_bounds__(256) void k_conv_dw(
    const float* __restrict__ sum, const float* __restrict__ cnt,
    const float* __restrict__ dww, float* __restrict__ xm2) {
  int byx = blockIdx.x;         // b*4096 + y*64 + x
  int c = threadIdx.x;
  int b = byx >> 12;
  int yx = byx & 4095;
  int y = yx >> 6, x = yx & 63;
  float acc = 0.f;
#pragma unroll
  for (int ky = 0; ky < 3; ++ky) {
    int iy = 2 * y - 1 + ky;
    if ((unsigned)iy >= 128u) continue;
#pragma unroll
    for (int kx = 0; kx < 3; ++kx) {
      int ix = 2 * x - 1 + kx;
      if ((unsigned)ix >= 128u) continue;
      size_t pidx = (size_t)b * 16384 + iy * 128 + ix;
      float m = sum[pidx * C0d + c] / (cnt[pidx] + 1e-6f);
      acc += m * dww[c * 9 + ky * 3 + kx];
    }
  }
  xm2[((size_t)b * 4096 + yx) * C0d + c] = acc;
}

// ---------- tiled NT f32 GEMM + BN epilogue (optionally + residual + relu) ----------
// C[m][n] = BN( sum_k A[m][k]*Bw[n][k] ) [+ resid, relu]
template <int KDIM, bool FUSE>
__global__ __launch_bounds__(256) void k_gemm_nt_bn(
    const float* __restrict__ A, const float* __restrict__ Bw,
    const float* __restrict__ g, const float* __restrict__ beta,
    const float* __restrict__ mean, const float* __restrict__ var,
    const float* __restrict__ resid, float* __restrict__ C, int M, int N) {
  __shared__ float As[16][68];
  __shared__ float Bs[16][68];
  const int t  = threadIdx.x;
  const int tx = t & 15;
  const int ty = t >> 4;
  const int m0 = blockIdx.x * 64;
  const int n0 = blockIdx.y * 64;
  const int lm = t >> 2;         // 0..63
  const int lk = (t & 3) * 4;    // 0,4,8,12
  float acc[4][4] = {};
  for (int kt = 0; kt < KDIM; kt += 16) {
    float4 av = *reinterpret_cast<const float4*>(&A[(size_t)(m0 + lm) * KDIM + kt + lk]);
    float4 bv = *reinterpret_cast<const float4*>(&Bw[(size_t)(n0 + lm) * KDIM + kt + lk]);
    As[lk + 0][lm] = av.x; As[lk + 1][lm] = av.y; As[lk + 2][lm] = av.z; As[lk + 3][lm] = av.w;
    Bs[lk + 0][lm] = bv.x; Bs[lk + 1][lm] = bv.y; Bs[lk + 2][lm] = bv.z; Bs[lk + 3][lm] = bv.w;
    __syncthreads();
#pragma unroll
    for (int k = 0; k < 16; ++k) {
      float4 a4 = *reinterpret_cast<const float4*>(&As[k][ty * 4]);
      float4 b4 = *reinterpret_cast<const float4*>(&Bs[k][tx * 4]);
      float aa[4] = {a4.x, a4.y, a4.z, a4.w};
      float bb[4] = {b4.x, b4.y, b4.z, b4.w};
#pragma unroll
      for (int i = 0; i < 4; ++i)
#pragma unroll
        for (int j = 0; j < 4; ++j) acc[i][j] += aa[i] * bb[j];
    }
    __syncthreads();
  }
#pragma unroll
  for (int j = 0; j < 4; ++j) {
    int n = n0 + tx * 4 + j;
    float s  = g[n] * rsqrtf(var[n] + 1e-5f);
    float sh = beta[n] - mean[n] * s;
#pragma unroll
    for (int i = 0; i < 4; ++i) {
      int m = m0 + ty * 4 + i;
      float v = acc[i][j] * s + sh;
      if (FUSE) {
        v += resid[(size_t)m * N + n];
        v = fmaxf(v, 0.f);
      }
      C[(size_t)m * N + n] = v;
    }
  }
}

// ---------- token_downup scatter for out0: num0 += src[b][idx1[bp]] * w0; den0 += w0 ----------
__global__ __launch_bounds__(256) void k_scatter0(
    const float* __restrict__ src, const int* __restrict__ idx1,
    const int* __restrict__ idx0, const float* __restrict__ w0,
    float* __restrict__ num0, float* __restrict__ den0) {
  int bp = blockIdx.x;
  int c  = threadIdx.x;
  int b  = bp >> 14;
  int ts = idx1[bp];             // source token [0, N1T)
  int td = idx0[bp];             // target token [0, N0T)
  float w = w0[bp];
  float v = src[((size_t)b * N1T + ts) * C0d + c] * w;
  atomicAdd(&num0[((size_t)b * N0T + td) * C0d + c], v);
  if (c == 0) atomicAdd(&den0[b * N0T + td], w);
}

// ---------- out0 = relu(x0 + num/(den+1e-6)) (in-place on d_out) ----------
__global__ __launch_bounds__(256) void k_finalize0(
    const float* __restrict__ x0, const float* __restrict__ den0, float* __restrict__ out0) {
  int row = blockIdx.x;          // b*N0T + n  (131072 rows)
  int c = threadIdx.x;
  size_t i = (size_t)row * C0d + c;
  float d = den0[row] + 1e-6f;
  float v = out0[i] / d + x0[i];
  out0[i] = fmaxf(v, 0.f);
}

// ---------- fused map2token + token_downup scatter (shared den1) ----------
__global__ __launch_bounds__(256) void k_scatter1(
    const float* __restrict__ xm2, const float* __restrict__ x0,
    const int* __restrict__ idx0, const int* __restrict__ idx1,
    const float* __restrict__ w1, const float* __restrict__ loc,
    float* __restrict__ xb_num, float* __restrict__ xd_num, float* __restrict__ den1) {
  int bp = blockIdx.x;
  int c  = threadIdx.x;
  int b  = bp >> 14;
  float lx = loc[2 * bp + 0];
  float ly = loc[2 * bp + 1];
  int pix = pix_idx(lx, ly, 64);
  int tt = idx1[bp];             // target [0, N1T)
  int ss = idx0[bp];             // source row of x0
  float w = w1[bp];
  float vb = xm2[((size_t)b * 4096 + pix) * C0d + c] * w;
  float vd = x0[((size_t)b * N0T + ss) * C0d + c] * w;
  size_t o = ((size_t)b * N1T + tt) * C0d + c;
  atomicAdd(&xb_num[o], vb);
  atomicAdd(&xd_num[o], vd);
  if (c == 0) atomicAdd(&den1[b * N1T + tt], w);
}

// ---------- xdf = bn1( xd/den * skip_w + xb/den ) ----------
__global__ __launch_bounds__(256) void k_finalize1(
    const float* __restrict__ xb_num, const float* __restrict__ xd_num,
    const float* __restrict__ den1, const float* __restrict__ skip_w,
    const float* __restrict__ g, const float* __restrict__ beta,
    const float* __restrict__ mean, const float* __restrict__ var,
    float* __restrict__ xdf) {
  int row = blockIdx.x;          // b*N1T + n  (32768 rows)
  int c = threadIdx.x;
  size_t i = (size_t)row * C0d + c;
  float d = den1[row] + 1e-6f;
  float v = (xd_num[i] / d) * skip_w[c] + xb_num[i] / d;
  float s  = g[c] * rsqrtf(var[c] + 1e-5f);
  float sh = beta[c] - mean[c] * s;
  xdf[i] = v * s + sh;
}

extern "C" void kernel_launch(void* const* d_in, const int* in_sizes, int n_in,
                              void* d_out, int out_size, void* d_ws, size_t ws_size,
                              hipStream_t stream) {
  const float* x0   = (const float*)d_in[0];
  const float* x1   = (const float*)d_in[1];
  const int*   idx0 = (const int*)d_in[2];
  const int*   idx1 = (const int*)d_in[3];
  const float* w0   = (const float*)d_in[4];
  const float* w1   = (const float*)d_in[5];
  const float* loc  = (const float*)d_in[6];
  const float* W01  = (const float*)d_in[7];
  const float* bn01_g = (const float*)d_in[8];
  const float* bn01_b = (const float*)d_in[9];
  const float* bn01_m = (const float*)d_in[10];
  const float* bn01_v = (const float*)d_in[11];
  const float* dw_w   = (const float*)d_in[12];
  const float* skip_w = (const float*)d_in[13];
  const float* bn1_g  = (const float*)d_in[14];
  const float* bn1_b  = (const float*)d_in[15];
  const float* bn1_m  = (const float*)d_in[16];
  const float* bn1_v  = (const float*)d_in[17];
  const float* conv_w = (const float*)d_in[18];
  const float* bn2_g  = (const float*)d_in[19];
  const float* bn2_b  = (const float*)d_in[20];
  const float* bn2_m  = (const float*)d_in[21];
  const float* bn2_v  = (const float*)d_in[22];
  // d_in[23], d_in[24] = H0, W0 (hardcoded 128)

  float* out = (float*)d_out;
  float* ws  = (float*)d_ws;

  // ---- workspace layout (floats) ----
  // region A (33,554,432 f): t2m_sum; later reused: src at +0 (8,388,608 f),
  //                          xdf at +8,388,608 f
  float* t2m_sum = ws;
  float* srcb    = ws;                       // alias: t2m_sum dead by then
  float* xdf     = ws + 8388608;             // alias inside region A
  float* t2m_cnt = ws + 33554432;            // 131072 f
  float* den0    = t2m_cnt + 131072;         // 131072 f
  float* den1    = den0 + 131072;            // 32768 f
  float* xm2     = den1 + 32768;             // 8,388,608 f
  const size_t ZBYTES = (33554432ull + 131072 + 131072 + 32768) * 4;   // accumulators

  // d_out layout: out0 = 33,554,432 f; out1 region doubles as xb_num|xd_num (2 x 8,388,608 f)
  float* num0   = out;
  float* out1   = out + 33554432;
  float* xb_num = out1;
  float* xd_num = out1 + 8388608;

  // ---- zero accumulators (graph-capturable memset nodes) ----
  hipMemsetAsync(d_ws, 0, ZBYTES, stream);
  hipMemsetAsync(d_out, 0, (size_t)out_size * 4, stream);

  const int nbp = Bb * NPIX;   // 131072

  // 1) token2map scatter (needs t2m_sum region A)
  k_scatter_t2m<<<nbp, 256, 0, stream>>>(x0, idx0, loc, t2m_sum, t2m_cnt);

  // 2) normalize + depthwise conv -> xm2 ; region A becomes free after this
  k_conv_dw<<<Bb * 4096, 256, 0, stream>>>(t2m_sum, t2m_cnt, dw_w, xm2);

  // 3) src = bn01(x1 @ W01^T)  [32768 x 256], into region A
  {
    dim3 grid(32768 / 64, 256 / 64);
    k_gemm_nt_bn<512, false><<<grid, 256, 0, stream>>>(
        x1, W01, bn01_g, bn01_b, bn01_m, bn01_v, nullptr, srcb, 32768, 256);
  }

  // 4) token_downup -> num0 (in d_out) / den0
  k_scatter0<<<nbp, 256, 0, stream>>>(srcb, idx1, idx0, w0, num0, den0);

  // 5) out0 = relu(x0 + num0/(den0+eps))  (in place)
  k_finalize0<<<Bb * N0T, 256, 0, stream>>>(x0, den0, num0);

  // 6) fused map2token + token_downup scatter -> xb_num/xd_num (in d_out out1 region), den1
  k_scatter1<<<nbp, 256, 0, stream>>>(xm2, x0, idx0, idx1, w1, loc, xb_num, xd_num, den1);

  // 7) xdf = bn1( xd/den * skip + xb/den )   [32768 x 256]
  k_finalize1<<<Bb * N1T, 256, 0, stream>>>(xb_num, xd_num, den1, skip_w,
                                            bn1_g, bn1_b, bn1_m, bn1_v, xdf);

  // 8) out1 = relu(x1 + bn2(xdf @ conv_w^T))  [32768 x 512]
  {
    dim3 grid(32768 / 64, 512 / 64);
    k_gemm_nt_bn<256, true><<<grid, 256, 0, stream>>>(
        xdf, conv_w, bn2_g, bn2_b, bn2_m, bn2_v, x1, out1, 32768, 512);
  }
}

// Round 2
// 617.101 us; speedup vs baseline: 1.5632x; 1.5632x over previous
//
#include <hip/hip_runtime.h>

#define Bb   8
#define NPIX 16384
#define N0T  16384
#define N1T  4096
#define C0d  256
#define C1d  512

// key space: [0,131072) pixel128 | [131072,262144) out0 tokens | [262144,294912) out1 tokens
#define NKEY_P 131072
#define NKEY_0 131072
#define NKEY_1 32768
#define NKEYS  294912          // 288 * 1024
#define SCAN_BLOCKS 288

// ---------- pixel index (matches jnp.round = round-half-even via rintf) ----------
__device__ __forceinline__ int pix_idx(float lx, float ly, int HW) {
  lx = fminf(fmaxf(lx, -1.f), 1.f);
  ly = fminf(fmaxf(ly, -1.f), 1.f);
  float half = (float)HW * 0.5f;
  float fx = (lx + 1.0f) * half - 0.5f;   // power-of-2 scale: exact
  float fy = (ly + 1.0f) * half - 0.5f;
  int px = (int)rintf(fx);
  int py = (int)rintf(fy);
  px = min(max(px, 0), HW - 1);
  py = min(max(py, 0), HW - 1);
  return py * HW + px;
}

// ---------- CSR build: histogram ----------
__global__ __launch_bounds__(256) void k_count(
    const int* __restrict__ idx0, const int* __restrict__ idx1,
    const float* __restrict__ loc, int* __restrict__ counts) {
  int e = blockIdx.x * 256 + threadIdx.x;     // 131072 entries
  int b = e >> 14;
  float lx = loc[2 * e + 0], ly = loc[2 * e + 1];
  int kp = b * 16384 + pix_idx(lx, ly, 128);
  int k0 = NKEY_P + b * 16384 + idx0[e];
  int k1 = NKEY_P + NKEY_0 + b * 4096 + idx1[e];
  atomicAdd(&counts[kp], 1);
  atomicAdd(&counts[k0], 1);
  atomicAdd(&counts[k1], 1);
}

// ---------- hierarchical exclusive scan (in place: counts -> offsets) ----------
__global__ __launch_bounds__(256) void k_scan_block(int* __restrict__ cnt, int* __restrict__ bsum) {
  __shared__ int s[256];
  const int tid = threadIdx.x;
  const int base = blockIdx.x * 1024 + tid * 4;
  int4 v = *reinterpret_cast<const int4*>(&cnt[base]);
  int t1 = v.x + v.y, t2 = t1 + v.z, t3 = t2 + v.w;
  s[tid] = t3;
  __syncthreads();
  for (int d = 1; d < 256; d <<= 1) {
    int add = (tid >= d) ? s[tid - d] : 0;
    __syncthreads();
    s[tid] += add;
    __syncthreads();
  }
  int excl = tid ? s[tid - 1] : 0;
  int4 o;
  o.x = excl; o.y = excl + v.x; o.z = excl + t1; o.w = excl + t2;
  *reinterpret_cast<int4*>(&cnt[base]) = o;
  if (tid == 255) bsum[blockIdx.x] = s[255];
}

__global__ __launch_bounds__(512) void k_scan_top(int* __restrict__ bsum) {
  __shared__ int s[512];
  const int tid = threadIdx.x;
  int v = (tid < SCAN_BLOCKS) ? bsum[tid] : 0;
  s[tid] = v;
  __syncthreads();
  for (int d = 1; d < 512; d <<= 1) {
    int add = (tid >= d) ? s[tid - d] : 0;
    __syncthreads();
    s[tid] += add;
    __syncthreads();
  }
  int excl = tid ? s[tid - 1] : 0;
  if (tid < SCAN_BLOCKS) bsum[tid] = excl;
}

__global__ __launch_bounds__(256) void k_scan_add(int* __restrict__ off, const int* __restrict__ bsum) {
  int add = bsum[blockIdx.x];
  const int base = blockIdx.x * 1024 + threadIdx.x * 4;
  int4 v = *reinterpret_cast<const int4*>(&off[base]);
  v.x += add; v.y += add; v.z += add; v.w += add;
  *reinterpret_cast<int4*>(&off[base]) = v;
}

// ---------- CSR fill ----------
__global__ __launch_bounds__(256) void k_fill(
    const int* __restrict__ idx0, const int* __restrict__ idx1,
    const float* __restrict__ w0, const float* __restrict__ w1,
    const float* __restrict__ loc, const int* __restrict__ offs,
    int* __restrict__ cursor, int* __restrict__ intA,
    int* __restrict__ intB, float* __restrict__ fW) {
  int e = blockIdx.x * 256 + threadIdx.x;
  int b = e >> 14;
  float lx = loc[2 * e + 0], ly = loc[2 * e + 1];
  int i0 = idx0[e], i1 = idx1[e];
  int kp = b * 16384 + pix_idx(lx, ly, 128);
  int k0 = NKEY_P + b * 16384 + i0;
  int k1 = NKEY_P + NKEY_0 + b * 4096 + i1;
  // CSR_P: list of x0 rows per 128x128 pixel
  int pP = offs[kp] + atomicAdd(&cursor[kp], 1);
  intA[pP] = b * 16384 + i0;
  // CSR_0: list of (srcb row, w0) per out0 token
  int p0 = offs[k0] + atomicAdd(&cursor[k0], 1);
  intA[p0] = b * 4096 + i1;
  fW[p0 - NKEY_P] = w0[e];
  // CSR_1: list of (xm2 row, x0 row, w1) per out1 token
  int p1 = offs[k1] + atomicAdd(&cursor[k1], 1);
  intA[p1] = b * 4096 + pix_idx(lx, ly, 64);
  intB[p1 - (NKEY_P + NKEY_0)] = b * 16384 + i0;
  fW[p1 - NKEY_P] = w1[e];
}

// ---------- fused token2map + normalize + depthwise 3x3 s2 -> xm2 [B*4096][C0] ----------
__global__ __launch_bounds__(256) void k_conv_fused(
    const float* __restrict__ x0, const int* __restrict__ offs,
    const int* __restrict__ lens, const int* __restrict__ intA,
    const float* __restrict__ dww, float* __restrict__ xm2) {
  int byx = blockIdx.x;          // b*4096 + y*64 + x
  int c = threadIdx.x;
  int b = byx >> 12;
  int yx = byx & 4095;
  int y = yx >> 6, x = yx & 63;
  float acc = 0.f;
#pragma unroll
  for (int ky = 0; ky < 3; ++ky) {
    int iy = 2 * y - 1 + ky;
    if ((unsigned)iy >= 128u) continue;
#pragma unroll
    for (int kx = 0; kx < 3; ++kx) {
      int ix = 2 * x - 1 + kx;
      if ((unsigned)ix >= 128u) continue;
      int key = b * 16384 + iy * 128 + ix;
      int st = offs[key];
      int ln = lens[key];
      float s = 0.f;
      for (int i = 0; i < ln; ++i)
        s += x0[(size_t)intA[st + i] * C0d + c];
      acc += (s / ((float)ln + 1e-6f)) * dww[c * 9 + ky * 3 + kx];
    }
  }
  xm2[(size_t)byx * C0d + c] = acc;
}

// ---------- tiled NT f32 GEMM + BN epilogue (optionally + residual + relu) ----------
template <int KDIM, bool FUSE>
__global__ __launch_bounds__(256) void k_gemm_nt_bn(
    const float* __restrict__ A, const float* __restrict__ Bw,
    const float* __restrict__ g, const float* __restrict__ beta,
    const float* __restrict__ mean, const float* __restrict__ var,
    const float* __restrict__ resid, float* __restrict__ C, int M, int N) {
  __shared__ float As[16][68];
  __shared__ float Bs[16][68];
  const int t  = threadIdx.x;
  const int tx = t & 15;
  const int ty = t >> 4;
  const int m0 = blockIdx.x * 64;
  const int n0 = blockIdx.y * 64;
  const int lm = t >> 2;
  const int lk = (t & 3) * 4;
  float acc[4][4] = {};
  for (int kt = 0; kt < KDIM; kt += 16) {
    float4 av = *reinterpret_cast<const float4*>(&A[(size_t)(m0 + lm) * KDIM + kt + lk]);
    float4 bv = *reinterpret_cast<const float4*>(&Bw[(size_t)(n0 + lm) * KDIM + kt + lk]);
    As[lk + 0][lm] = av.x; As[lk + 1][lm] = av.y; As[lk + 2][lm] = av.z; As[lk + 3][lm] = av.w;
    Bs[lk + 0][lm] = bv.x; Bs[lk + 1][lm] = bv.y; Bs[lk + 2][lm] = bv.z; Bs[lk + 3][lm] = bv.w;
    __syncthreads();
#pragma unroll
    for (int k = 0; k < 16; ++k) {
      float4 a4 = *reinterpret_cast<const float4*>(&As[k][ty * 4]);
      float4 b4 = *reinterpret_cast<const float4*>(&Bs[k][tx * 4]);
      float aa[4] = {a4.x, a4.y, a4.z, a4.w};
      float bb[4] = {b4.x, b4.y, b4.z, b4.w};
#pragma unroll
      for (int i = 0; i < 4; ++i)
#pragma unroll
        for (int j = 0; j < 4; ++j) acc[i][j] += aa[i] * bb[j];
    }
    __syncthreads();
  }
#pragma unroll
  for (int j = 0; j < 4; ++j) {
    int n = n0 + tx * 4 + j;
    float s  = g[n] * rsqrtf(var[n] + 1e-5f);
    float sh = beta[n] - mean[n] * s;
#pragma unroll
    for (int i = 0; i < 4; ++i) {
      int m = m0 + ty * 4 + i;
      float v = acc[i][j] * s + sh;
      if (FUSE) {
        v += resid[(size_t)m * N + n];
        v = fmaxf(v, 0.f);
      }
      C[(size_t)m * N + n] = v;
    }
  }
}

// ---------- out0 = relu(x0 + gather(srcb,w)/(den+eps)) ----------
__global__ __launch_bounds__(256) void k_out0(
    const float* __restrict__ srcb, const float* __restrict__ x0,
    const int* __restrict__ offs, const int* __restrict__ lens,
    const int* __restrict__ intA, const float* __restrict__ fW,
    float* __restrict__ out0) {
  int row = blockIdx.x;          // 131072
  int c = threadIdx.x;
  int key = NKEY_P + row;
  int st = offs[key];
  int ln = lens[key];
  float acc = 0.f, den = 0.f;
  for (int i = 0; i < ln; ++i) {
    int sr = intA[st + i];
    float w = fW[st + i - NKEY_P];
    acc += srcb[(size_t)sr * C0d + c] * w;
    den += w;
  }
  size_t o = (size_t)row * C0d + c;
  out0[o] = fmaxf(x0[o] + acc / (den + 1e-6f), 0.f);
}

// ---------- xdf = bn1( gather_d/den * skip + gather_b/den ) ----------
__global__ __launch_bounds__(256) void k_out1_pre(
    const float* __restrict__ xm2, const float* __restrict__ x0,
    const int* __restrict__ offs, const int* __restrict__ lens,
    const int* __restrict__ intA, const int* __restrict__ intB,
    const float* __restrict__ fW, const float* __restrict__ skip_w,
    const float* __restrict__ g, const float* __restrict__ beta,
    const float* __restrict__ mean, const float* __restrict__ var,
    float* __restrict__ xdf) {
  int row = blockIdx.x;          // 32768
  int c = threadIdx.x;
  int key = NKEY_P + NKEY_0 + row;
  int st = offs[key];
  int ln = lens[key];
  float ab = 0.f, ad = 0.f, den = 0.f;
  for (int i = 0; i < ln; ++i) {
    int pr = intA[st + i];
    int sr = intB[st + i - (NKEY_P + NKEY_0)];
    float w = fW[st + i - NKEY_P];
    ab += xm2[(size_t)pr * C0d + c] * w;
    ad += x0[(size_t)sr * C0d + c] * w;
    den += w;
  }
  float inv = 1.f / (den + 1e-6f);
  float v = (ad * inv) * skip_w[c] + ab * inv;
  float s  = g[c] * rsqrtf(var[c] + 1e-5f);
  float sh = beta[c] - mean[c] * s;
  xdf[(size_t)row * C0d + c] = v * s + sh;
}

extern "C" void kernel_launch(void* const* d_in, const int* in_sizes, int n_in,
                              void* d_out, int out_size, void* d_ws, size_t ws_size,
                              hipStream_t stream) {
  const float* x0   = (const float*)d_in[0];
  const float* x1   = (const float*)d_in[1];
  const int*   idx0 = (const int*)d_in[2];
  const int*   idx1 = (const int*)d_in[3];
  const float* w0   = (const float*)d_in[4];
  const float* w1   = (const float*)d_in[5];
  const float* loc  = (const float*)d_in[6];
  const float* W01  = (const float*)d_in[7];
  const float* bn01_g = (const float*)d_in[8];
  const float* bn01_b = (const float*)d_in[9];
  const float* bn01_m = (const float*)d_in[10];
  const float* bn01_v = (const float*)d_in[11];
  const float* dw_w   = (const float*)d_in[12];
  const float* skip_w = (const float*)d_in[13];
  const float* bn1_g  = (const float*)d_in[14];
  const float* bn1_b  = (const float*)d_in[15];
  const float* bn1_m  = (const float*)d_in[16];
  const float* bn1_v  = (const float*)d_in[17];
  const float* conv_w = (const float*)d_in[18];
  const float* bn2_g  = (const float*)d_in[19];
  const float* bn2_b  = (const float*)d_in[20];
  const float* bn2_m  = (const float*)d_in[21];
  const float* bn2_v  = (const float*)d_in[22];

  float* out = (float*)d_out;
  float* num0 = out;                       // out0 region [131072 x 256]
  float* out1 = out + 33554432;            // out1 region [32768 x 512]

  // ---- workspace layout ----
  int*   counts = (int*)d_ws;              // 294912 (becomes offsets after scan)
  int*   cursor = counts + NKEYS;          // 294912 (becomes lengths after fill)
  int*   bsum   = cursor + NKEYS;          // 512
  int*   intA   = bsum + 512;              // 393216
  int*   intB   = intA + 393216;           // 131072
  float* fW     = (float*)(intB + 131072); // 262144
  float* xm2    = fW + 262144;             // 8,388,608
  float* srcb   = xm2 + 8388608;           // 8,388,608
  float* xdf    = srcb + 8388608;          // 8,388,608
  const size_t ZBYTES = (size_t)(NKEYS * 2 + 512) * sizeof(int);

  hipMemsetAsync(d_ws, 0, ZBYTES, stream);

  const int nbp = Bb * NPIX;               // 131072

  // CSR build
  k_count<<<nbp / 256, 256, 0, stream>>>(idx0, idx1, loc, counts);
  k_scan_block<<<SCAN_BLOCKS, 256, 0, stream>>>(counts, bsum);
  k_scan_top<<<1, 512, 0, stream>>>(bsum);
  k_scan_add<<<SCAN_BLOCKS, 256, 0, stream>>>(counts, bsum);
  k_fill<<<nbp / 256, 256, 0, stream>>>(idx0, idx1, w0, w1, loc, counts, cursor,
                                        intA, intB, fW);

  // fused token2map + dw-conv -> xm2
  k_conv_fused<<<Bb * 4096, 256, 0, stream>>>(x0, counts, cursor, intA, dw_w, xm2);

  // src = bn01(x1 @ W01^T)
  {
    dim3 grid(32768 / 64, 256 / 64);
    k_gemm_nt_bn<512, false><<<grid, 256, 0, stream>>>(
        x1, W01, bn01_g, bn01_b, bn01_m, bn01_v, nullptr, srcb, 32768, 256);
  }

  // out0 = relu(x0 + gather(srcb))
  k_out0<<<nbp, 256, 0, stream>>>(srcb, x0, counts, cursor, intA, fW, num0);

  // xdf = bn1(gather_d*skip + gather_b)
  k_out1_pre<<<Bb * N1T, 256, 0, stream>>>(xm2, x0, counts, cursor, intA, intB, fW,
                                           skip_w, bn1_g, bn1_b, bn1_m, bn1_v, xdf);

  // out1 = relu(x1 + bn2(xdf @ conv_w^T))
  {
    dim3 grid(32768 / 64, 512 / 64);
    k_gemm_nt_bn<256, true><<<grid, 256, 0, stream>>>(
        xdf, conv_w, bn2_g, bn2_b, bn2_m, bn2_v, x1, out1, 32768, 512);
  }
}

// Round 3
// 341.867 us; speedup vs baseline: 2.8217x; 1.8051x over previous
//
#include <hip/hip_runtime.h>

#define Bb   8
#define NPIX 16384
#define N0T  16384
#define N1T  4096
#define C0d  256
#define C1d  512

#define NKEY_P 131072
#define NKEY_0 131072
#define NKEY_1 32768
#define NKEYS  294912
#define SCAN_BLOCKS 288

typedef __attribute__((ext_vector_type(8))) short bf16x8;
typedef __attribute__((ext_vector_type(4))) float f32x4;

// ---------- helpers ----------
__device__ __forceinline__ int pix_idx(float lx, float ly, int HW) {
  lx = fminf(fmaxf(lx, -1.f), 1.f);
  ly = fminf(fmaxf(ly, -1.f), 1.f);
  float half = (float)HW * 0.5f;
  int px = (int)rintf((lx + 1.0f) * half - 0.5f);
  int py = (int)rintf((ly + 1.0f) * half - 0.5f);
  px = min(max(px, 0), HW - 1);
  py = min(max(py, 0), HW - 1);
  return py * HW + px;
}

__device__ __forceinline__ short f2bf(float f) {
  unsigned u = __float_as_uint(f);
  unsigned r = (u + 0x7fffu + ((u >> 16) & 1u)) >> 16;
  return (short)r;
}

// ---------- CSR build ----------
__global__ __launch_bounds__(256) void k_count(
    const int* __restrict__ idx0, const int* __restrict__ idx1,
    const float* __restrict__ loc, int* __restrict__ counts) {
  int e = blockIdx.x * 256 + threadIdx.x;
  int b = e >> 14;
  float lx = loc[2 * e + 0], ly = loc[2 * e + 1];
  int kp = b * 16384 + pix_idx(lx, ly, 128);
  int k0 = NKEY_P + b * 16384 + idx0[e];
  int k1 = NKEY_P + NKEY_0 + b * 4096 + idx1[e];
  atomicAdd(&counts[kp], 1);
  atomicAdd(&counts[k0], 1);
  atomicAdd(&counts[k1], 1);
}

__global__ __launch_bounds__(256) void k_scan_block(int* __restrict__ cnt, int* __restrict__ bsum) {
  __shared__ int s[256];
  const int tid = threadIdx.x;
  const int base = blockIdx.x * 1024 + tid * 4;
  int4 v = *reinterpret_cast<const int4*>(&cnt[base]);
  int t1 = v.x + v.y, t2 = t1 + v.z, t3 = t2 + v.w;
  s[tid] = t3;
  __syncthreads();
  for (int d = 1; d < 256; d <<= 1) {
    int add = (tid >= d) ? s[tid - d] : 0;
    __syncthreads();
    s[tid] += add;
    __syncthreads();
  }
  int excl = tid ? s[tid - 1] : 0;
  int4 o;
  o.x = excl; o.y = excl + v.x; o.z = excl + t1; o.w = excl + t2;
  *reinterpret_cast<int4*>(&cnt[base]) = o;
  if (tid == 255) bsum[blockIdx.x] = s[255];
}

__global__ __launch_bounds__(512) void k_scan_top(int* __restrict__ bsum) {
  __shared__ int s[512];
  const int tid = threadIdx.x;
  int v = (tid < SCAN_BLOCKS) ? bsum[tid] : 0;
  s[tid] = v;
  __syncthreads();
  for (int d = 1; d < 512; d <<= 1) {
    int add = (tid >= d) ? s[tid - d] : 0;
    __syncthreads();
    s[tid] += add;
    __syncthreads();
  }
  int excl = tid ? s[tid - 1] : 0;
  if (tid < SCAN_BLOCKS) bsum[tid] = excl;
}

__global__ __launch_bounds__(256) void k_scan_add(int* __restrict__ off, const int* __restrict__ bsum) {
  int add = bsum[blockIdx.x];
  const int base = blockIdx.x * 1024 + threadIdx.x * 4;
  int4 v = *reinterpret_cast<const int4*>(&off[base]);
  v.x += add; v.y += add; v.z += add; v.w += add;
  *reinterpret_cast<int4*>(&off[base]) = v;
}

__global__ __launch_bounds__(256) void k_fill(
    const int* __restrict__ idx0, const int* __restrict__ idx1,
    const float* __restrict__ w0, const float* __restrict__ w1,
    const float* __restrict__ loc, const int* __restrict__ offs,
    int* __restrict__ cursor, int* __restrict__ intA,
    int* __restrict__ intB, float* __restrict__ fW) {
  int e = blockIdx.x * 256 + threadIdx.x;
  int b = e >> 14;
  float lx = loc[2 * e + 0], ly = loc[2 * e + 1];
  int i0 = idx0[e], i1 = idx1[e];
  int kp = b * 16384 + pix_idx(lx, ly, 128);
  int k0 = NKEY_P + b * 16384 + i0;
  int k1 = NKEY_P + NKEY_0 + b * 4096 + i1;
  int pP = offs[kp] + atomicAdd(&cursor[kp], 1);
  intA[pP] = b * 16384 + i0;
  int p0 = offs[k0] + atomicAdd(&cursor[k0], 1);
  intA[p0] = b * 4096 + i1;
  fW[p0 - NKEY_P] = w0[e];
  int p1 = offs[k1] + atomicAdd(&cursor[k1], 1);
  intA[p1] = b * 4096 + pix_idx(lx, ly, 64);
  intB[p1 - (NKEY_P + NKEY_0)] = b * 16384 + i0;
  fW[p1 - NKEY_P] = w1[e];
}

// ---------- dw-weight transpose: dwT[k][c] = dw_w[c*9+k] ----------
__global__ __launch_bounds__(256) void k_prepw(const float* __restrict__ dww, float* __restrict__ dwT) {
  int k = blockIdx.x;          // 0..8
  int c = threadIdx.x;
  dwT[k * 256 + c] = dww[c * 9 + k];
}

// ---------- fused token2map + normalize + dw 3x3 s2 (float4/lane) ----------
__global__ __launch_bounds__(256) void k_conv_v4(
    const float* __restrict__ x0, const int* __restrict__ offs,
    const int* __restrict__ lens, const int* __restrict__ intA,
    const float* __restrict__ dwT, float* __restrict__ xm2) {
  int byx = blockIdx.x * 4 + (threadIdx.x >> 6);
  int lane = threadIdx.x & 63;
  int c4 = lane * 4;
  int b = byx >> 12;
  int yx = byx & 4095;
  int y = yx >> 6, x = yx & 63;
  float ax = 0.f, ay = 0.f, az = 0.f, aw = 0.f;
#pragma unroll
  for (int ky = 0; ky < 3; ++ky) {
    int iy = 2 * y - 1 + ky;
    if ((unsigned)iy >= 128u) continue;
#pragma unroll
    for (int kx = 0; kx < 3; ++kx) {
      int ix = 2 * x - 1 + kx;
      if ((unsigned)ix >= 128u) continue;
      int key = b * 16384 + iy * 128 + ix;
      int st = offs[key];
      int ln = lens[key];
      float sx = 0.f, sy = 0.f, sz = 0.f, sw = 0.f;
      for (int i = 0; i < ln; ++i) {
        int row = intA[st + i];
        float4 v = *reinterpret_cast<const float4*>(&x0[(size_t)row * C0d + c4]);
        sx += v.x; sy += v.y; sz += v.z; sw += v.w;
      }
      float inv = 1.f / ((float)ln + 1e-6f);
      float4 w = *reinterpret_cast<const float4*>(&dwT[(ky * 3 + kx) * 256 + c4]);
      ax += sx * inv * w.x; ay += sy * inv * w.y;
      az += sz * inv * w.z; aw += sw * inv * w.w;
    }
  }
  float4 o; o.x = ax; o.y = ay; o.z = az; o.w = aw;
  *reinterpret_cast<float4*>(&xm2[(size_t)byx * C0d + c4]) = o;
}

// ---------- bf16 MFMA GEMM: C[m][n] = BN(sum_k A[m][k]*Bw[n][k]) [+resid,relu] ----------
// BM=128, BN=64, BK=32; 256 threads = 4 waves (2 m x 2 n)
template <int KDIM, bool FUSE, bool ABF16>
__global__ __launch_bounds__(256) void k_gemm_mfma(
    const void* __restrict__ Av, const float* __restrict__ Bw,
    const float* __restrict__ g, const float* __restrict__ beta,
    const float* __restrict__ mean, const float* __restrict__ var,
    const float* __restrict__ resid, float* __restrict__ C, int N) {
  __shared__ __align__(16) short Als[4][128][8];   // [k/8][m][k%8]
  __shared__ __align__(16) short Bls[4][64][8];
  const int t = threadIdx.x;
  const int lane = t & 63;
  const int wave = t >> 6;
  const int wm = wave >> 1;        // 0..1
  const int wn = wave & 1;         // 0..1
  const int m0 = blockIdx.x * 128;
  const int n0 = blockIdx.y * 64;
  const int l15 = lane & 15;
  const int kb = lane >> 4;
  const int arow = t >> 1, ahalf = t & 1;   // A staging: 16 k-elems/thread
  const int brow = t >> 2, bq = t & 3;      // B staging: 8  k-elems/thread
  f32x4 acc[4][2] = {};

  for (int kt = 0; kt < KDIM; kt += 32) {
    // ---- stage A ----
    if (ABF16) {
      const short* A = (const short*)Av;
      size_t base = (size_t)(m0 + arow) * KDIM + kt + ahalf * 16;
      bf16x8 v0 = *reinterpret_cast<const bf16x8*>(&A[base]);
      bf16x8 v1 = *reinterpret_cast<const bf16x8*>(&A[base + 8]);
      *reinterpret_cast<bf16x8*>(&Als[ahalf * 2 + 0][arow][0]) = v0;
      *reinterpret_cast<bf16x8*>(&Als[ahalf * 2 + 1][arow][0]) = v1;
    } else {
      const float* A = (const float*)Av;
      size_t base = (size_t)(m0 + arow) * KDIM + kt + ahalf * 16;
      float4 f0 = *reinterpret_cast<const float4*>(&A[base + 0]);
      float4 f1 = *reinterpret_cast<const float4*>(&A[base + 4]);
      float4 f2 = *reinterpret_cast<const float4*>(&A[base + 8]);
      float4 f3 = *reinterpret_cast<const float4*>(&A[base + 12]);
      bf16x8 v0 = { f2bf(f0.x), f2bf(f0.y), f2bf(f0.z), f2bf(f0.w),
                    f2bf(f1.x), f2bf(f1.y), f2bf(f1.z), f2bf(f1.w) };
      bf16x8 v1 = { f2bf(f2.x), f2bf(f2.y), f2bf(f2.z), f2bf(f2.w),
                    f2bf(f3.x), f2bf(f3.y), f2bf(f3.z), f2bf(f3.w) };
      *reinterpret_cast<bf16x8*>(&Als[ahalf * 2 + 0][arow][0]) = v0;
      *reinterpret_cast<bf16x8*>(&Als[ahalf * 2 + 1][arow][0]) = v1;
    }
    // ---- stage B (f32 -> bf16) ----
    {
      size_t base = (size_t)(n0 + brow) * KDIM + kt + bq * 8;
      float4 g0 = *reinterpret_cast<const float4*>(&Bw[base + 0]);
      float4 g1 = *reinterpret_cast<const float4*>(&Bw[base + 4]);
      bf16x8 w = { f2bf(g0.x), f2bf(g0.y), f2bf(g0.z), f2bf(g0.w),
                   f2bf(g1.x), f2bf(g1.y), f2bf(g1.z), f2bf(g1.w) };
      *reinterpret_cast<bf16x8*>(&Bls[bq][brow][0]) = w;
    }
    __syncthreads();
    bf16x8 af[4], bfr[2];
#pragma unroll
    for (int r = 0; r < 4; ++r)
      af[r] = *reinterpret_cast<const bf16x8*>(&Als[kb][wm * 64 + r * 16 + l15][0]);
#pragma unroll
    for (int s = 0; s < 2; ++s)
      bfr[s] = *reinterpret_cast<const bf16x8*>(&Bls[kb][wn * 32 + s * 16 + l15][0]);
#pragma unroll
    for (int r = 0; r < 4; ++r)
#pragma unroll
      for (int s = 0; s < 2; ++s)
        acc[r][s] = __builtin_amdgcn_mfma_f32_16x16x32_bf16(af[r], bfr[s], acc[r][s], 0, 0, 0);
    __syncthreads();
  }

  // ---- epilogue: C/D layout col=lane&15, row=(lane>>4)*4+reg ----
  const int r0 = (lane >> 4) * 4;
#pragma unroll
  for (int s = 0; s < 2; ++s) {
    int col = n0 + wn * 32 + s * 16 + l15;
    float sc = g[col] * rsqrtf(var[col] + 1e-5f);
    float sh = beta[col] - mean[col] * sc;
#pragma unroll
    for (int r = 0; r < 4; ++r) {
      int rowb = m0 + wm * 64 + r * 16 + r0;
#pragma unroll
      for (int j = 0; j < 4; ++j) {
        int row = rowb + j;
        float v = acc[r][s][j] * sc + sh;
        if (FUSE) {
          v += resid[(size_t)row * N + col];
          v = fmaxf(v, 0.f);
        }
        C[(size_t)row * N + col] = v;
      }
    }
  }
}

// ---------- out0 = relu(x0 + gather(srcb,w)/(den+eps))  (float4/lane) ----------
__global__ __launch_bounds__(256) void k_out0_v4(
    const float* __restrict__ srcb, const float* __restrict__ x0,
    const int* __restrict__ offs, const int* __restrict__ lens,
    const int* __restrict__ intA, const float* __restrict__ fW,
    float* __restrict__ out0) {
  int row = blockIdx.x * 4 + (threadIdx.x >> 6);
  int lane = threadIdx.x & 63;
  int c4 = lane * 4;
  int key = NKEY_P + row;
  int st = offs[key];
  int ln = lens[key];
  float ax = 0.f, ay = 0.f, az = 0.f, aw = 0.f, den = 0.f;
  for (int i = 0; i < ln; ++i) {
    int sr = intA[st + i];
    float w = fW[st + i - NKEY_P];
    float4 v = *reinterpret_cast<const float4*>(&srcb[(size_t)sr * C0d + c4]);
    ax += v.x * w; ay += v.y * w; az += v.z * w; aw += v.w * w;
    den += w;
  }
  float inv = 1.f / (den + 1e-6f);
  size_t o = (size_t)row * C0d + c4;
  float4 xv = *reinterpret_cast<const float4*>(&x0[o]);
  float4 r;
  r.x = fmaxf(xv.x + ax * inv, 0.f);
  r.y = fmaxf(xv.y + ay * inv, 0.f);
  r.z = fmaxf(xv.z + az * inv, 0.f);
  r.w = fmaxf(xv.w + aw * inv, 0.f);
  *reinterpret_cast<float4*>(&out0[o]) = r;
}

// ---------- xdf(bf16) = bn1( gd/den * skip + gb/den )  (float4/lane) ----------
__global__ __launch_bounds__(256) void k_out1_pre_v4(
    const float* __restrict__ xm2, const float* __restrict__ x0,
    const int* __restrict__ offs, const int* __restrict__ lens,
    const int* __restrict__ intA, const int* __restrict__ intB,
    const float* __restrict__ fW, const float* __restrict__ skip_w,
    const float* __restrict__ g, const float* __restrict__ beta,
    const float* __restrict__ mean, const float* __restrict__ var,
    short* __restrict__ xdf) {
  int row = blockIdx.x * 4 + (threadIdx.x >> 6);
  int lane = threadIdx.x & 63;
  int c4 = lane * 4;
  int key = NKEY_P + NKEY_0 + row;
  int st = offs[key];
  int ln = lens[key];
  float bx = 0.f, by = 0.f, bz = 0.f, bw = 0.f;
  float dx = 0.f, dy = 0.f, dz = 0.f, dw = 0.f, den = 0.f;
  for (int i = 0; i < ln; ++i) {
    int pr = intA[st + i];
    int sr = intB[st + i - (NKEY_P + NKEY_0)];
    float w = fW[st + i - NKEY_P];
    float4 vb = *reinterpret_cast<const float4*>(&xm2[(size_t)pr * C0d + c4]);
    float4 vd = *reinterpret_cast<const float4*>(&x0[(size_t)sr * C0d + c4]);
    bx += vb.x * w; by += vb.y * w; bz += vb.z * w; bw += vb.w * w;
    dx += vd.x * w; dy += vd.y * w; dz += vd.z * w; dw += vd.w * w;
    den += w;
  }
  float inv = 1.f / (den + 1e-6f);
  float4 sk = *reinterpret_cast<const float4*>(&skip_w[c4]);
  float4 gg = *reinterpret_cast<const float4*>(&g[c4]);
  float4 bb = *reinterpret_cast<const float4*>(&beta[c4]);
  float4 mm = *reinterpret_cast<const float4*>(&mean[c4]);
  float4 vv = *reinterpret_cast<const float4*>(&var[c4]);
  float s0 = gg.x * rsqrtf(vv.x + 1e-5f), h0 = bb.x - mm.x * s0;
  float s1 = gg.y * rsqrtf(vv.y + 1e-5f), h1 = bb.y - mm.y * s1;
  float s2 = gg.z * rsqrtf(vv.z + 1e-5f), h2 = bb.z - mm.z * s2;
  float s3 = gg.w * rsqrtf(vv.w + 1e-5f), h3 = bb.w - mm.w * s3;
  short4 o;
  o.x = f2bf((dx * inv * sk.x + bx * inv) * s0 + h0);
  o.y = f2bf((dy * inv * sk.y + by * inv) * s1 + h1);
  o.z = f2bf((dz * inv * sk.z + bz * inv) * s2 + h2);
  o.w = f2bf((dw * inv * sk.w + bw * inv) * s3 + h3);
  *reinterpret_cast<short4*>(&xdf[(size_t)row * C0d + c4]) = o;
}

extern "C" void kernel_launch(void* const* d_in, const int* in_sizes, int n_in,
                              void* d_out, int out_size, void* d_ws, size_t ws_size,
                              hipStream_t stream) {
  const float* x0   = (const float*)d_in[0];
  const float* x1   = (const float*)d_in[1];
  const int*   idx0 = (const int*)d_in[2];
  const int*   idx1 = (const int*)d_in[3];
  const float* w0   = (const float*)d_in[4];
  const float* w1   = (const float*)d_in[5];
  const float* loc  = (const float*)d_in[6];
  const float* W01  = (const float*)d_in[7];
  const float* bn01_g = (const float*)d_in[8];
  const float* bn01_b = (const float*)d_in[9];
  const float* bn01_m = (const float*)d_in[10];
  const float* bn01_v = (const float*)d_in[11];
  const float* dw_w   = (const float*)d_in[12];
  const float* skip_w = (const float*)d_in[13];
  const float* bn1_g  = (const float*)d_in[14];
  const float* bn1_b  = (const float*)d_in[15];
  const float* bn1_m  = (const float*)d_in[16];
  const float* bn1_v  = (const float*)d_in[17];
  const float* conv_w = (const float*)d_in[18];
  const float* bn2_g  = (const float*)d_in[19];
  const float* bn2_b  = (const float*)d_in[20];
  const float* bn2_m  = (const float*)d_in[21];
  const float* bn2_v  = (const float*)d_in[22];

  float* out = (float*)d_out;
  float* num0 = out;                       // out0 [131072 x 256]
  float* out1 = out + 33554432;            // out1 [32768 x 512]

  // ---- workspace layout ----
  int*   counts = (int*)d_ws;              // NKEYS (-> offsets)
  int*   cursor = counts + NKEYS;          // NKEYS (-> lengths)
  int*   bsum   = cursor + NKEYS;          // 512
  int*   intA   = bsum + 512;              // 393216
  int*   intB   = intA + 393216;           // 131072
  float* fW     = (float*)(intB + 131072); // 262144
  float* dwT    = fW + 262144;             // 2560 (2304 used)
  float* xm2    = dwT + 2560;              // 8,388,608
  float* srcb   = xm2 + 8388608;           // 8,388,608
  short* xdf    = (short*)(srcb + 8388608);// 8,388,608 shorts (bf16)
  const size_t ZBYTES = (size_t)(NKEYS * 2 + 512) * sizeof(int);

  hipMemsetAsync(d_ws, 0, ZBYTES, stream);

  const int nbp = Bb * NPIX;               // 131072

  // CSR build
  k_count<<<nbp / 256, 256, 0, stream>>>(idx0, idx1, loc, counts);
  k_scan_block<<<SCAN_BLOCKS, 256, 0, stream>>>(counts, bsum);
  k_scan_top<<<1, 512, 0, stream>>>(bsum);
  k_scan_add<<<SCAN_BLOCKS, 256, 0, stream>>>(counts, bsum);
  k_fill<<<nbp / 256, 256, 0, stream>>>(idx0, idx1, w0, w1, loc, counts, cursor,
                                        intA, intB, fW);
  k_prepw<<<9, 256, 0, stream>>>(dw_w, dwT);

  // fused token2map + dw-conv -> xm2
  k_conv_v4<<<Bb * 4096 / 4, 256, 0, stream>>>(x0, counts, cursor, intA, dwT, xm2);

  // src = bn01(x1 @ W01^T)   [32768 x 256], bf16 MFMA
  {
    dim3 grid(32768 / 128, 256 / 64);
    k_gemm_mfma<512, false, false><<<grid, 256, 0, stream>>>(
        (const void*)x1, W01, bn01_g, bn01_b, bn01_m, bn01_v, nullptr, srcb, 256);
  }

  // out0 = relu(x0 + gather(srcb))
  k_out0_v4<<<nbp / 4, 256, 0, stream>>>(srcb, x0, counts, cursor, intA, fW, num0);

  // xdf(bf16) = bn1(gather_d*skip + gather_b)
  k_out1_pre_v4<<<Bb * N1T / 4, 256, 0, stream>>>(xm2, x0, counts, cursor, intA, intB,
                                                  fW, skip_w, bn1_g, bn1_b, bn1_m, bn1_v,
                                                  xdf);

  // out1 = relu(x1 + bn2(xdf @ conv_w^T))  [32768 x 512], bf16 MFMA
  {
    dim3 grid(32768 / 128, 512 / 64);
    k_gemm_mfma<256, true, true><<<grid, 256, 0, stream>>>(
        (const void*)xdf, conv_w, bn2_g, bn2_b, bn2_m, bn2_v, x1, out1, 512);
  }
}

// Round 4
// 340.693 us; speedup vs baseline: 2.8314x; 1.0034x over previous
//
#include <hip/hip_runtime.h>

#define Bb   8
#define NPIX 16384
#define N0T  16384
#define N1T  4096
#define C0d  256
#define C1d  512

#define NKEY_P 131072
#define NKEY_0 131072
#define NKEY_1 32768
#define NKEYS  294912
#define SCAN_BLOCKS 288

// zero region: counts + cursor + bsum = NKEYS*2 + 512 ints
#define NZINT (NKEYS * 2 + 512)
#define NZI4  ((NZINT + 3) / 4)

typedef __attribute__((ext_vector_type(8))) short bf16x8;
typedef __attribute__((ext_vector_type(4))) float f32x4;

// ---------- helpers ----------
__device__ __forceinline__ int pix_idx(float lx, float ly, int HW) {
  lx = fminf(fmaxf(lx, -1.f), 1.f);
  ly = fminf(fmaxf(ly, -1.f), 1.f);
  float half = (float)HW * 0.5f;
  int px = (int)rintf((lx + 1.0f) * half - 0.5f);
  int py = (int)rintf((ly + 1.0f) * half - 0.5f);
  px = min(max(px, 0), HW - 1);
  py = min(max(py, 0), HW - 1);
  return py * HW + px;
}

__device__ __forceinline__ short f2bf(float f) {
  unsigned u = __float_as_uint(f);
  unsigned r = (u + 0x7fffu + ((u >> 16) & 1u)) >> 16;
  return (short)r;
}

// ---------- zero CSR counters (replaces pathological rocclr fill) ----------
__global__ __launch_bounds__(256) void k_zero(int4* __restrict__ p) {
  int i = blockIdx.x * 256 + threadIdx.x;
  if (i < NZI4) p[i] = int4{0, 0, 0, 0};
}

// ---------- CSR build ----------
__global__ __launch_bounds__(256) void k_count(
    const int* __restrict__ idx0, const int* __restrict__ idx1,
    const float* __restrict__ loc, int* __restrict__ counts) {
  int e = blockIdx.x * 256 + threadIdx.x;
  int b = e >> 14;
  float lx = loc[2 * e + 0], ly = loc[2 * e + 1];
  int kp = b * 16384 + pix_idx(lx, ly, 128);
  int k0 = NKEY_P + b * 16384 + idx0[e];
  int k1 = NKEY_P + NKEY_0 + b * 4096 + idx1[e];
  atomicAdd(&counts[kp], 1);
  atomicAdd(&counts[k0], 1);
  atomicAdd(&counts[k1], 1);
}

__global__ __launch_bounds__(256) void k_scan_block(int* __restrict__ cnt, int* __restrict__ bsum) {
  __shared__ int s[256];
  const int tid = threadIdx.x;
  const int base = blockIdx.x * 1024 + tid * 4;
  int4 v = *reinterpret_cast<const int4*>(&cnt[base]);
  int t1 = v.x + v.y, t2 = t1 + v.z, t3 = t2 + v.w;
  s[tid] = t3;
  __syncthreads();
  for (int d = 1; d < 256; d <<= 1) {
    int add = (tid >= d) ? s[tid - d] : 0;
    __syncthreads();
    s[tid] += add;
    __syncthreads();
  }
  int excl = tid ? s[tid - 1] : 0;
  int4 o;
  o.x = excl; o.y = excl + v.x; o.z = excl + t1; o.w = excl + t2;
  *reinterpret_cast<int4*>(&cnt[base]) = o;
  if (tid == 255) bsum[blockIdx.x] = s[255];
}

__global__ __launch_bounds__(512) void k_scan_top(int* __restrict__ bsum) {
  __shared__ int s[512];
  const int tid = threadIdx.x;
  int v = (tid < SCAN_BLOCKS) ? bsum[tid] : 0;
  s[tid] = v;
  __syncthreads();
  for (int d = 1; d < 512; d <<= 1) {
    int add = (tid >= d) ? s[tid - d] : 0;
    __syncthreads();
    s[tid] += add;
    __syncthreads();
  }
  int excl = tid ? s[tid - 1] : 0;
  if (tid < SCAN_BLOCKS) bsum[tid] = excl;
}

__global__ __launch_bounds__(256) void k_scan_add(int* __restrict__ off, const int* __restrict__ bsum) {
  int add = bsum[blockIdx.x];
  const int base = blockIdx.x * 1024 + threadIdx.x * 4;
  int4 v = *reinterpret_cast<const int4*>(&off[base]);
  v.x += add; v.y += add; v.z += add; v.w += add;
  *reinterpret_cast<int4*>(&off[base]) = v;
}

__global__ __launch_bounds__(256) void k_fill(
    const int* __restrict__ idx0, const int* __restrict__ idx1,
    const float* __restrict__ w0, const float* __restrict__ w1,
    const float* __restrict__ loc, const int* __restrict__ offs,
    int* __restrict__ cursor, int* __restrict__ intA,
    int* __restrict__ intB, float* __restrict__ fW) {
  int e = blockIdx.x * 256 + threadIdx.x;
  int b = e >> 14;
  float lx = loc[2 * e + 0], ly = loc[2 * e + 1];
  int i0 = idx0[e], i1 = idx1[e];
  int kp = b * 16384 + pix_idx(lx, ly, 128);
  int k0 = NKEY_P + b * 16384 + i0;
  int k1 = NKEY_P + NKEY_0 + b * 4096 + i1;
  int pP = offs[kp] + atomicAdd(&cursor[kp], 1);
  intA[pP] = b * 16384 + i0;
  int p0 = offs[k0] + atomicAdd(&cursor[k0], 1);
  intA[p0] = b * 4096 + i1;
  fW[p0 - NKEY_P] = w0[e];
  int p1 = offs[k1] + atomicAdd(&cursor[k1], 1);
  intA[p1] = b * 4096 + pix_idx(lx, ly, 64);
  intB[p1 - (NKEY_P + NKEY_0)] = b * 16384 + i0;
  fW[p1 - NKEY_P] = w1[e];
}

// ---------- dw-weight transpose: dwT[k][c] = dw_w[c*9+k] ----------
__global__ __launch_bounds__(256) void k_prepw(const float* __restrict__ dww, float* __restrict__ dwT) {
  int k = blockIdx.x;          // 0..8
  int c = threadIdx.x;
  dwT[k * 256 + c] = dww[c * 9 + k];
}

// ---------- fused token2map + normalize + dw 3x3 s2 (float4/lane) ----------
__global__ __launch_bounds__(256) void k_conv_v4(
    const float* __restrict__ x0, const int* __restrict__ offs,
    const int* __restrict__ lens, const int* __restrict__ intA,
    const float* __restrict__ dwT, float* __restrict__ xm2) {
  int byx = blockIdx.x * 4 + (threadIdx.x >> 6);
  int lane = threadIdx.x & 63;
  int c4 = lane * 4;
  int b = byx >> 12;
  int yx = byx & 4095;
  int y = yx >> 6, x = yx & 63;
  float ax = 0.f, ay = 0.f, az = 0.f, aw = 0.f;
#pragma unroll
  for (int ky = 0; ky < 3; ++ky) {
    int iy = 2 * y - 1 + ky;
    if ((unsigned)iy >= 128u) continue;
#pragma unroll
    for (int kx = 0; kx < 3; ++kx) {
      int ix = 2 * x - 1 + kx;
      if ((unsigned)ix >= 128u) continue;
      int key = b * 16384 + iy * 128 + ix;
      int st = offs[key];
      int ln = lens[key];
      float sx = 0.f, sy = 0.f, sz = 0.f, sw = 0.f;
      for (int i = 0; i < ln; ++i) {
        int row = intA[st + i];
        float4 v = *reinterpret_cast<const float4*>(&x0[(size_t)row * C0d + c4]);
        sx += v.x; sy += v.y; sz += v.z; sw += v.w;
      }
      float inv = 1.f / ((float)ln + 1e-6f);
      float4 w = *reinterpret_cast<const float4*>(&dwT[(ky * 3 + kx) * 256 + c4]);
      ax += sx * inv * w.x; ay += sy * inv * w.y;
      az += sz * inv * w.z; aw += sw * inv * w.w;
    }
  }
  float4 o; o.x = ax; o.y = ay; o.z = az; o.w = aw;
  *reinterpret_cast<float4*>(&xm2[(size_t)byx * C0d + c4]) = o;
}

// ---------- bf16 MFMA GEMM: C[m][n] = BN(sum_k A[m][k]*Bw[n][k]) [+resid,relu] ----------
// BM=128, BN=64, BK=32; 256 threads = 4 waves (2 m x 2 n)
template <int KDIM, bool FUSE, bool ABF16>
__global__ __launch_bounds__(256) void k_gemm_mfma(
    const void* __restrict__ Av, const float* __restrict__ Bw,
    const float* __restrict__ g, const float* __restrict__ beta,
    const float* __restrict__ mean, const float* __restrict__ var,
    const float* __restrict__ resid, float* __restrict__ C, int N) {
  __shared__ __align__(16) short Als[4][128][8];   // [k/8][m][k%8]
  __shared__ __align__(16) short Bls[4][64][8];
  const int t = threadIdx.x;
  const int lane = t & 63;
  const int wave = t >> 6;
  const int wm = wave >> 1;
  const int wn = wave & 1;
  const int m0 = blockIdx.x * 128;
  const int n0 = blockIdx.y * 64;
  const int l15 = lane & 15;
  const int kb = lane >> 4;
  const int arow = t >> 1, ahalf = t & 1;
  const int brow = t >> 2, bq = t & 3;
  f32x4 acc[4][2] = {};

  for (int kt = 0; kt < KDIM; kt += 32) {
    if (ABF16) {
      const short* A = (const short*)Av;
      size_t base = (size_t)(m0 + arow) * KDIM + kt + ahalf * 16;
      bf16x8 v0 = *reinterpret_cast<const bf16x8*>(&A[base]);
      bf16x8 v1 = *reinterpret_cast<const bf16x8*>(&A[base + 8]);
      *reinterpret_cast<bf16x8*>(&Als[ahalf * 2 + 0][arow][0]) = v0;
      *reinterpret_cast<bf16x8*>(&Als[ahalf * 2 + 1][arow][0]) = v1;
    } else {
      const float* A = (const float*)Av;
      size_t base = (size_t)(m0 + arow) * KDIM + kt + ahalf * 16;
      float4 f0 = *reinterpret_cast<const float4*>(&A[base + 0]);
      float4 f1 = *reinterpret_cast<const float4*>(&A[base + 4]);
      float4 f2 = *reinterpret_cast<const float4*>(&A[base + 8]);
      float4 f3 = *reinterpret_cast<const float4*>(&A[base + 12]);
      bf16x8 v0 = { f2bf(f0.x), f2bf(f0.y), f2bf(f0.z), f2bf(f0.w),
                    f2bf(f1.x), f2bf(f1.y), f2bf(f1.z), f2bf(f1.w) };
      bf16x8 v1 = { f2bf(f2.x), f2bf(f2.y), f2bf(f2.z), f2bf(f2.w),
                    f2bf(f3.x), f2bf(f3.y), f2bf(f3.z), f2bf(f3.w) };
      *reinterpret_cast<bf16x8*>(&Als[ahalf * 2 + 0][arow][0]) = v0;
      *reinterpret_cast<bf16x8*>(&Als[ahalf * 2 + 1][arow][0]) = v1;
    }
    {
      size_t base = (size_t)(n0 + brow) * KDIM + kt + bq * 8;
      float4 g0 = *reinterpret_cast<const float4*>(&Bw[base + 0]);
      float4 g1 = *reinterpret_cast<const float4*>(&Bw[base + 4]);
      bf16x8 w = { f2bf(g0.x), f2bf(g0.y), f2bf(g0.z), f2bf(g0.w),
                   f2bf(g1.x), f2bf(g1.y), f2bf(g1.z), f2bf(g1.w) };
      *reinterpret_cast<bf16x8*>(&Bls[bq][brow][0]) = w;
    }
    __syncthreads();
    bf16x8 af[4], bfr[2];
#pragma unroll
    for (int r = 0; r < 4; ++r)
      af[r] = *reinterpret_cast<const bf16x8*>(&Als[kb][wm * 64 + r * 16 + l15][0]);
#pragma unroll
    for (int s = 0; s < 2; ++s)
      bfr[s] = *reinterpret_cast<const bf16x8*>(&Bls[kb][wn * 32 + s * 16 + l15][0]);
#pragma unroll
    for (int r = 0; r < 4; ++r)
#pragma unroll
      for (int s = 0; s < 2; ++s)
        acc[r][s] = __builtin_amdgcn_mfma_f32_16x16x32_bf16(af[r], bfr[s], acc[r][s], 0, 0, 0);
    __syncthreads();
  }

  const int r0 = (lane >> 4) * 4;
#pragma unroll
  for (int s = 0; s < 2; ++s) {
    int col = n0 + wn * 32 + s * 16 + l15;
    float sc = g[col] * rsqrtf(var[col] + 1e-5f);
    float sh = beta[col] - mean[col] * sc;
#pragma unroll
    for (int r = 0; r < 4; ++r) {
      int rowb = m0 + wm * 64 + r * 16 + r0;
#pragma unroll
      for (int j = 0; j < 4; ++j) {
        int row = rowb + j;
        float v = acc[r][s][j] * sc + sh;
        if (FUSE) {
          v += resid[(size_t)row * N + col];
          v = fmaxf(v, 0.f);
        }
        C[(size_t)row * N + col] = v;
      }
    }
  }
}

// ---------- out0 = relu(x0 + gather(srcb,w)/(den+eps))  (float4/lane) ----------
__global__ __launch_bounds__(256) void k_out0_v4(
    const float* __restrict__ srcb, const float* __restrict__ x0,
    const int* __restrict__ offs, const int* __restrict__ lens,
    const int* __restrict__ intA, const float* __restrict__ fW,
    float* __restrict__ out0) {
  int row = blockIdx.x * 4 + (threadIdx.x >> 6);
  int lane = threadIdx.x & 63;
  int c4 = lane * 4;
  int key = NKEY_P + row;
  int st = offs[key];
  int ln = lens[key];
  float ax = 0.f, ay = 0.f, az = 0.f, aw = 0.f, den = 0.f;
  for (int i = 0; i < ln; ++i) {
    int sr = intA[st + i];
    float w = fW[st + i - NKEY_P];
    float4 v = *reinterpret_cast<const float4*>(&srcb[(size_t)sr * C0d + c4]);
    ax += v.x * w; ay += v.y * w; az += v.z * w; aw += v.w * w;
    den += w;
  }
  float inv = 1.f / (den + 1e-6f);
  size_t o = (size_t)row * C0d + c4;
  float4 xv = *reinterpret_cast<const float4*>(&x0[o]);
  float4 r;
  r.x = fmaxf(xv.x + ax * inv, 0.f);
  r.y = fmaxf(xv.y + ay * inv, 0.f);
  r.z = fmaxf(xv.z + az * inv, 0.f);
  r.w = fmaxf(xv.w + aw * inv, 0.f);
  *reinterpret_cast<float4*>(&out0[o]) = r;
}

// ---------- xdf(bf16) = bn1( gd/den * skip + gb/den )  (float4/lane) ----------
__global__ __launch_bounds__(256) void k_out1_pre_v4(
    const float* __restrict__ xm2, const float* __restrict__ x0,
    const int* __restrict__ offs, const int* __restrict__ lens,
    const int* __restrict__ intA, const int* __restrict__ intB,
    const float* __restrict__ fW, const float* __restrict__ skip_w,
    const float* __restrict__ g, const float* __restrict__ beta,
    const float* __restrict__ mean, const float* __restrict__ var,
    short* __restrict__ xdf) {
  int row = blockIdx.x * 4 + (threadIdx.x >> 6);
  int lane = threadIdx.x & 63;
  int c4 = lane * 4;
  int key = NKEY_P + NKEY_0 + row;
  int st = offs[key];
  int ln = lens[key];
  float bx = 0.f, by = 0.f, bz = 0.f, bw = 0.f;
  float dx = 0.f, dy = 0.f, dz = 0.f, dw = 0.f, den = 0.f;
  for (int i = 0; i < ln; ++i) {
    int pr = intA[st + i];
    int sr = intB[st + i - (NKEY_P + NKEY_0)];
    float w = fW[st + i - NKEY_P];
    float4 vb = *reinterpret_cast<const float4*>(&xm2[(size_t)pr * C0d + c4]);
    float4 vd = *reinterpret_cast<const float4*>(&x0[(size_t)sr * C0d + c4]);
    bx += vb.x * w; by += vb.y * w; bz += vb.z * w; bw += vb.w * w;
    dx += vd.x * w; dy += vd.y * w; dz += vd.z * w; dw += vd.w * w;
    den += w;
  }
  float inv = 1.f / (den + 1e-6f);
  float4 sk = *reinterpret_cast<const float4*>(&skip_w[c4]);
  float4 gg = *reinterpret_cast<const float4*>(&g[c4]);
  float4 bb = *reinterpret_cast<const float4*>(&beta[c4]);
  float4 mm = *reinterpret_cast<const float4*>(&mean[c4]);
  float4 vv = *reinterpret_cast<const float4*>(&var[c4]);
  float s0 = gg.x * rsqrtf(vv.x + 1e-5f), h0 = bb.x - mm.x * s0;
  float s1 = gg.y * rsqrtf(vv.y + 1e-5f), h1 = bb.y - mm.y * s1;
  float s2 = gg.z * rsqrtf(vv.z + 1e-5f), h2 = bb.z - mm.z * s2;
  float s3 = gg.w * rsqrtf(vv.w + 1e-5f), h3 = bb.w - mm.w * s3;
  short4 o;
  o.x = f2bf((dx * inv * sk.x + bx * inv) * s0 + h0);
  o.y = f2bf((dy * inv * sk.y + by * inv) * s1 + h1);
  o.z = f2bf((dz * inv * sk.z + bz * inv) * s2 + h2);
  o.w = f2bf((dw * inv * sk.w + bw * inv) * s3 + h3);
  *reinterpret_cast<short4*>(&xdf[(size_t)row * C0d + c4]) = o;
}

extern "C" void kernel_launch(void* const* d_in, const int* in_sizes, int n_in,
                              void* d_out, int out_size, void* d_ws, size_t ws_size,
                              hipStream_t stream) {
  const float* x0   = (const float*)d_in[0];
  const float* x1   = (const float*)d_in[1];
  const int*   idx0 = (const int*)d_in[2];
  const int*   idx1 = (const int*)d_in[3];
  const float* w0   = (const float*)d_in[4];
  const float* w1   = (const float*)d_in[5];
  const float* loc  = (const float*)d_in[6];
  const float* W01  = (const float*)d_in[7];
  const float* bn01_g = (const float*)d_in[8];
  const float* bn01_b = (const float*)d_in[9];
  const float* bn01_m = (const float*)d_in[10];
  const float* bn01_v = (const float*)d_in[11];
  const float* dw_w   = (const float*)d_in[12];
  const float* skip_w = (const float*)d_in[13];
  const float* bn1_g  = (const float*)d_in[14];
  const float* bn1_b  = (const float*)d_in[15];
  const float* bn1_m  = (const float*)d_in[16];
  const float* bn1_v  = (const float*)d_in[17];
  const float* conv_w = (const float*)d_in[18];
  const float* bn2_g  = (const float*)d_in[19];
  const float* bn2_b  = (const float*)d_in[20];
  const float* bn2_m  = (const float*)d_in[21];
  const float* bn2_v  = (const float*)d_in[22];

  float* out = (float*)d_out;
  float* num0 = out;                       // out0 [131072 x 256]
  float* out1 = out + 33554432;            // out1 [32768 x 512]

  // ---- workspace layout ----
  int*   counts = (int*)d_ws;              // NKEYS (-> offsets)
  int*   cursor = counts + NKEYS;          // NKEYS (-> lengths)
  int*   bsum   = cursor + NKEYS;          // 512
  int*   intA   = bsum + 512;              // 393216
  int*   intB   = intA + 393216;           // 131072
  float* fW     = (float*)(intB + 131072); // 262144
  float* dwT    = fW + 262144;             // 2560 (2304 used)
  float* xm2    = dwT + 2560;              // 8,388,608
  float* srcb   = xm2 + 8388608;           // 8,388,608
  short* xdf    = (short*)(srcb + 8388608);// 8,388,608 shorts (bf16)

  const int nbp = Bb * NPIX;               // 131072

  // zero CSR counters with our own kernel (rocclr small-fill was 117 us!)
  k_zero<<<(NZI4 + 255) / 256, 256, 0, stream>>>((int4*)d_ws);

  // CSR build
  k_count<<<nbp / 256, 256, 0, stream>>>(idx0, idx1, loc, counts);
  k_scan_block<<<SCAN_BLOCKS, 256, 0, stream>>>(counts, bsum);
  k_scan_top<<<1, 512, 0, stream>>>(bsum);
  k_scan_add<<<SCAN_BLOCKS, 256, 0, stream>>>(counts, bsum);
  k_fill<<<nbp / 256, 256, 0, stream>>>(idx0, idx1, w0, w1, loc, counts, cursor,
                                        intA, intB, fW);
  k_prepw<<<9, 256, 0, stream>>>(dw_w, dwT);

  // fused token2map + dw-conv -> xm2
  k_conv_v4<<<Bb * 4096 / 4, 256, 0, stream>>>(x0, counts, cursor, intA, dwT, xm2);

  // src = bn01(x1 @ W01^T)   [32768 x 256], bf16 MFMA
  {
    dim3 grid(32768 / 128, 256 / 64);
    k_gemm_mfma<512, false, false><<<grid, 256, 0, stream>>>(
        (const void*)x1, W01, bn01_g, bn01_b, bn01_m, bn01_v, nullptr, srcb, 256);
  }

  // out0 = relu(x0 + gather(srcb))
  k_out0_v4<<<nbp / 4, 256, 0, stream>>>(srcb, x0, counts, cursor, intA, fW, num0);

  // xdf(bf16) = bn1(gather_d*skip + gather_b)
  k_out1_pre_v4<<<Bb * N1T / 4, 256, 0, stream>>>(xm2, x0, counts, cursor, intA, intB,
                                                  fW, skip_w, bn1_g, bn1_b, bn1_m, bn1_v,
                                                  xdf);

  // out1 = relu(x1 + bn2(xdf @ conv_w^T))  [32768 x 512], bf16 MFMA
  {
    dim3 grid(32768 / 128, 512 / 64);
    k_gemm_mfma<256, true, true><<<grid, 256, 0, stream>>>(
        (const void*)xdf, conv_w, bn2_g, bn2_b, bn2_m, bn2_v, x1, out1, 512);
  }
}

// Round 5
// 325.976 us; speedup vs baseline: 2.9592x; 1.0451x over previous
//
#include <hip/hip_runtime.h>
#include <hip/hip_bf16.h>

#define Bb   8
#define NPIX 16384
#define N0T  16384
#define N1T  4096
#define C0d  256
#define C1d  512

#define NKEY_P 131072
#define NKEY_0 131072
#define NKEY_1 32768
#define NKEYS  294912
#define SCAN_BLOCKS 288

// zero region: counts + cursor + bsum = NKEYS*2 + 512 ints
#define NZINT (NKEYS * 2 + 512)
#define NZI4  ((NZINT + 3) / 4)

typedef __attribute__((ext_vector_type(8))) short bf16x8;
typedef __attribute__((ext_vector_type(4))) float f32x4;

// ---------- helpers ----------
__device__ __forceinline__ int pix_idx(float lx, float ly, int HW) {
  lx = fminf(fmaxf(lx, -1.f), 1.f);
  ly = fminf(fmaxf(ly, -1.f), 1.f);
  float half = (float)HW * 0.5f;
  int px = (int)rintf((lx + 1.0f) * half - 0.5f);
  int py = (int)rintf((ly + 1.0f) * half - 0.5f);
  px = min(max(px, 0), HW - 1);
  py = min(max(py, 0), HW - 1);
  return py * HW + px;
}

// RNE f32->bf16 via HIP cast: compiler fuses adjacent pairs into v_cvt_pk_bf16_f32
__device__ __forceinline__ short f2bf(float f) {
  union { __hip_bfloat16 h; short s; } u;
  u.h = __float2bfloat16(f);
  return u.s;
}
__device__ __forceinline__ float bf2f(short s) {
  return __uint_as_float(((unsigned)(unsigned short)s) << 16);
}

// ---------- zero CSR counters ----------
__global__ __launch_bounds__(256) void k_zero(int4* __restrict__ p) {
  int i = blockIdx.x * 256 + threadIdx.x;
  if (i < NZI4) p[i] = int4{0, 0, 0, 0};
}

// ---------- CSR build ----------
__global__ __launch_bounds__(256) void k_count(
    const int* __restrict__ idx0, const int* __restrict__ idx1,
    const float* __restrict__ loc, int* __restrict__ counts) {
  int e = blockIdx.x * 256 + threadIdx.x;
  int b = e >> 14;
  float lx = loc[2 * e + 0], ly = loc[2 * e + 1];
  int kp = b * 16384 + pix_idx(lx, ly, 128);
  int k0 = NKEY_P + b * 16384 + idx0[e];
  int k1 = NKEY_P + NKEY_0 + b * 4096 + idx1[e];
  atomicAdd(&counts[kp], 1);
  atomicAdd(&counts[k0], 1);
  atomicAdd(&counts[k1], 1);
}

__global__ __launch_bounds__(256) void k_scan_block(int* __restrict__ cnt, int* __restrict__ bsum) {
  __shared__ int s[256];
  const int tid = threadIdx.x;
  const int base = blockIdx.x * 1024 + tid * 4;
  int4 v = *reinterpret_cast<const int4*>(&cnt[base]);
  int t1 = v.x + v.y, t2 = t1 + v.z, t3 = t2 + v.w;
  s[tid] = t3;
  __syncthreads();
  for (int d = 1; d < 256; d <<= 1) {
    int add = (tid >= d) ? s[tid - d] : 0;
    __syncthreads();
    s[tid] += add;
    __syncthreads();
  }
  int excl = tid ? s[tid - 1] : 0;
  int4 o;
  o.x = excl; o.y = excl + v.x; o.z = excl + t1; o.w = excl + t2;
  *reinterpret_cast<int4*>(&cnt[base]) = o;
  if (tid == 255) bsum[blockIdx.x] = s[255];
}

__global__ __launch_bounds__(512) void k_scan_top(int* __restrict__ bsum) {
  __shared__ int s[512];
  const int tid = threadIdx.x;
  int v = (tid < SCAN_BLOCKS) ? bsum[tid] : 0;
  s[tid] = v;
  __syncthreads();
  for (int d = 1; d < 512; d <<= 1) {
    int add = (tid >= d) ? s[tid - d] : 0;
    __syncthreads();
    s[tid] += add;
    __syncthreads();
  }
  int excl = tid ? s[tid - 1] : 0;
  if (tid < SCAN_BLOCKS) bsum[tid] = excl;
}

__global__ __launch_bounds__(256) void k_scan_add(int* __restrict__ off, const int* __restrict__ bsum) {
  int add = bsum[blockIdx.x];
  const int base = blockIdx.x * 1024 + threadIdx.x * 4;
  int4 v = *reinterpret_cast<const int4*>(&off[base]);
  v.x += add; v.y += add; v.z += add; v.w += add;
  *reinterpret_cast<int4*>(&off[base]) = v;
}

__global__ __launch_bounds__(256) void k_fill(
    const int* __restrict__ idx0, const int* __restrict__ idx1,
    const float* __restrict__ w0, const float* __restrict__ w1,
    const float* __restrict__ loc, const int* __restrict__ offs,
    int* __restrict__ cursor, int* __restrict__ intA,
    int* __restrict__ intB, float* __restrict__ fW) {
  int e = blockIdx.x * 256 + threadIdx.x;
  int b = e >> 14;
  float lx = loc[2 * e + 0], ly = loc[2 * e + 1];
  int i0 = idx0[e], i1 = idx1[e];
  int kp = b * 16384 + pix_idx(lx, ly, 128);
  int k0 = NKEY_P + b * 16384 + i0;
  int k1 = NKEY_P + NKEY_0 + b * 4096 + i1;
  int pP = offs[kp] + atomicAdd(&cursor[kp], 1);
  intA[pP] = b * 16384 + i0;
  int p0 = offs[k0] + atomicAdd(&cursor[k0], 1);
  intA[p0] = b * 4096 + i1;
  fW[p0 - NKEY_P] = w0[e];
  int p1 = offs[k1] + atomicAdd(&cursor[k1], 1);
  intA[p1] = b * 4096 + pix_idx(lx, ly, 64);
  intB[p1 - (NKEY_P + NKEY_0)] = b * 16384 + i0;
  fW[p1 - NKEY_P] = w1[e];
}

// ---------- dw-weight transpose: dwT[k][c] = dw_w[c*9+k] ----------
__global__ __launch_bounds__(256) void k_prepw(const float* __restrict__ dww, float* __restrict__ dwT) {
  int k = blockIdx.x;
  int c = threadIdx.x;
  dwT[k * 256 + c] = dww[c * 9 + k];
}

// ---------- fused token2map + normalize + dw 3x3 s2 -> xm2 bf16 [B*4096][C0] ----------
__global__ __launch_bounds__(256) void k_conv_v4(
    const float* __restrict__ x0, const int* __restrict__ offs,
    const int* __restrict__ lens, const int* __restrict__ intA,
    const float* __restrict__ dwT, short* __restrict__ xm2) {
  int byx = blockIdx.x * 4 + (threadIdx.x >> 6);
  int lane = threadIdx.x & 63;
  int c4 = lane * 4;
  int b = byx >> 12;
  int yx = byx & 4095;
  int y = yx >> 6, x = yx & 63;
  float ax = 0.f, ay = 0.f, az = 0.f, aw = 0.f;
#pragma unroll
  for (int ky = 0; ky < 3; ++ky) {
    int iy = 2 * y - 1 + ky;
    if ((unsigned)iy >= 128u) continue;
#pragma unroll
    for (int kx = 0; kx < 3; ++kx) {
      int ix = 2 * x - 1 + kx;
      if ((unsigned)ix >= 128u) continue;
      int key = b * 16384 + iy * 128 + ix;
      int st = offs[key];
      int ln = lens[key];
      float sx = 0.f, sy = 0.f, sz = 0.f, sw = 0.f;
      for (int i = 0; i < ln; ++i) {
        int row = intA[st + i];
        float4 v = *reinterpret_cast<const float4*>(&x0[(size_t)row * C0d + c4]);
        sx += v.x; sy += v.y; sz += v.z; sw += v.w;
      }
      float inv = 1.f / ((float)ln + 1e-6f);
      float4 w = *reinterpret_cast<const float4*>(&dwT[(ky * 3 + kx) * 256 + c4]);
      ax += sx * inv * w.x; ay += sy * inv * w.y;
      az += sz * inv * w.z; aw += sw * inv * w.w;
    }
  }
  short4 o;
  o.x = f2bf(ax); o.y = f2bf(ay); o.z = f2bf(az); o.w = f2bf(aw);
  *reinterpret_cast<short4*>(&xm2[(size_t)byx * C0d + c4]) = o;
}

// ---------- bf16 MFMA GEMM: C[m][n] = BN(sum_k A[m][k]*Bw[n][k]) [+resid,relu] ----------
// BM=128, BN=64, BK=32; 256 threads = 4 waves (2 m x 2 n)
template <int KDIM, bool FUSE, bool ABF16, bool OBF16>
__global__ __launch_bounds__(256) void k_gemm_mfma(
    const void* __restrict__ Av, const float* __restrict__ Bw,
    const float* __restrict__ g, const float* __restrict__ beta,
    const float* __restrict__ mean, const float* __restrict__ var,
    const float* __restrict__ resid, void* __restrict__ Cv, int N) {
  __shared__ __align__(16) short Als[4][128][8];   // [k/8][m][k%8]
  __shared__ __align__(16) short Bls[4][64][8];
  const int t = threadIdx.x;
  const int lane = t & 63;
  const int wave = t >> 6;
  const int wm = wave >> 1;
  const int wn = wave & 1;
  const int m0 = blockIdx.x * 128;
  const int n0 = blockIdx.y * 64;
  const int l15 = lane & 15;
  const int kb = lane >> 4;
  const int arow = t >> 1, ahalf = t & 1;
  const int brow = t >> 2, bq = t & 3;
  f32x4 acc[4][2] = {};

  for (int kt = 0; kt < KDIM; kt += 32) {
    if (ABF16) {
      const short* A = (const short*)Av;
      size_t base = (size_t)(m0 + arow) * KDIM + kt + ahalf * 16;
      bf16x8 v0 = *reinterpret_cast<const bf16x8*>(&A[base]);
      bf16x8 v1 = *reinterpret_cast<const bf16x8*>(&A[base + 8]);
      *reinterpret_cast<bf16x8*>(&Als[ahalf * 2 + 0][arow][0]) = v0;
      *reinterpret_cast<bf16x8*>(&Als[ahalf * 2 + 1][arow][0]) = v1;
    } else {
      const float* A = (const float*)Av;
      size_t base = (size_t)(m0 + arow) * KDIM + kt + ahalf * 16;
      float4 f0 = *reinterpret_cast<const float4*>(&A[base + 0]);
      float4 f1 = *reinterpret_cast<const float4*>(&A[base + 4]);
      float4 f2 = *reinterpret_cast<const float4*>(&A[base + 8]);
      float4 f3 = *reinterpret_cast<const float4*>(&A[base + 12]);
      bf16x8 v0 = { f2bf(f0.x), f2bf(f0.y), f2bf(f0.z), f2bf(f0.w),
                    f2bf(f1.x), f2bf(f1.y), f2bf(f1.z), f2bf(f1.w) };
      bf16x8 v1 = { f2bf(f2.x), f2bf(f2.y), f2bf(f2.z), f2bf(f2.w),
                    f2bf(f3.x), f2bf(f3.y), f2bf(f3.z), f2bf(f3.w) };
      *reinterpret_cast<bf16x8*>(&Als[ahalf * 2 + 0][arow][0]) = v0;
      *reinterpret_cast<bf16x8*>(&Als[ahalf * 2 + 1][arow][0]) = v1;
    }
    {
      size_t base = (size_t)(n0 + brow) * KDIM + kt + bq * 8;
      float4 g0 = *reinterpret_cast<const float4*>(&Bw[base + 0]);
      float4 g1 = *reinterpret_cast<const float4*>(&Bw[base + 4]);
      bf16x8 w = { f2bf(g0.x), f2bf(g0.y), f2bf(g0.z), f2bf(g0.w),
                   f2bf(g1.x), f2bf(g1.y), f2bf(g1.z), f2bf(g1.w) };
      *reinterpret_cast<bf16x8*>(&Bls[bq][brow][0]) = w;
    }
    __syncthreads();
    bf16x8 af[4], bfr[2];
#pragma unroll
    for (int r = 0; r < 4; ++r)
      af[r] = *reinterpret_cast<const bf16x8*>(&Als[kb][wm * 64 + r * 16 + l15][0]);
#pragma unroll
    for (int s = 0; s < 2; ++s)
      bfr[s] = *reinterpret_cast<const bf16x8*>(&Bls[kb][wn * 32 + s * 16 + l15][0]);
#pragma unroll
    for (int r = 0; r < 4; ++r)
#pragma unroll
      for (int s = 0; s < 2; ++s)
        acc[r][s] = __builtin_amdgcn_mfma_f32_16x16x32_bf16(af[r], bfr[s], acc[r][s], 0, 0, 0);
    __syncthreads();
  }

  const int r0 = (lane >> 4) * 4;
#pragma unroll
  for (int s = 0; s < 2; ++s) {
    int col = n0 + wn * 32 + s * 16 + l15;
    float sc = g[col] * rsqrtf(var[col] + 1e-5f);
    float sh = beta[col] - mean[col] * sc;
#pragma unroll
    for (int r = 0; r < 4; ++r) {
      int rowb = m0 + wm * 64 + r * 16 + r0;
#pragma unroll
      for (int j = 0; j < 4; ++j) {
        int row = rowb + j;
        float v = acc[r][s][j] * sc + sh;
        if (FUSE) {
          v += resid[(size_t)row * N + col];
          v = fmaxf(v, 0.f);
        }
        if (OBF16) ((short*)Cv)[(size_t)row * N + col] = f2bf(v);
        else       ((float*)Cv)[(size_t)row * N + col] = v;
      }
    }
  }
}

// ---------- out0 = relu(x0 + gather(srcb_bf16,w)/(den+eps)) ----------
__global__ __launch_bounds__(256) void k_out0_v4(
    const short* __restrict__ srcb, const float* __restrict__ x0,
    const int* __restrict__ offs, const int* __restrict__ lens,
    const int* __restrict__ intA, const float* __restrict__ fW,
    float* __restrict__ out0) {
  int row = blockIdx.x * 4 + (threadIdx.x >> 6);
  int lane = threadIdx.x & 63;
  int c4 = lane * 4;
  int key = NKEY_P + row;
  int st = offs[key];
  int ln = lens[key];
  float ax = 0.f, ay = 0.f, az = 0.f, aw = 0.f, den = 0.f;
  for (int i = 0; i < ln; ++i) {
    int sr = intA[st + i];
    float w = fW[st + i - NKEY_P];
    short4 v = *reinterpret_cast<const short4*>(&srcb[(size_t)sr * C0d + c4]);
    ax += bf2f(v.x) * w; ay += bf2f(v.y) * w;
    az += bf2f(v.z) * w; aw += bf2f(v.w) * w;
    den += w;
  }
  float inv = 1.f / (den + 1e-6f);
  size_t o = (size_t)row * C0d + c4;
  float4 xv = *reinterpret_cast<const float4*>(&x0[o]);
  float4 r;
  r.x = fmaxf(xv.x + ax * inv, 0.f);
  r.y = fmaxf(xv.y + ay * inv, 0.f);
  r.z = fmaxf(xv.z + az * inv, 0.f);
  r.w = fmaxf(xv.w + aw * inv, 0.f);
  *reinterpret_cast<float4*>(&out0[o]) = r;
}

// ---------- xdf(bf16) = bn1( gd/den * skip + gb/den ) ----------
__global__ __launch_bounds__(256) void k_out1_pre_v4(
    const short* __restrict__ xm2, const float* __restrict__ x0,
    const int* __restrict__ offs, const int* __restrict__ lens,
    const int* __restrict__ intA, const int* __restrict__ intB,
    const float* __restrict__ fW, const float* __restrict__ skip_w,
    const float* __restrict__ g, const float* __restrict__ beta,
    const float* __restrict__ mean, const float* __restrict__ var,
    short* __restrict__ xdf) {
  int row = blockIdx.x * 4 + (threadIdx.x >> 6);
  int lane = threadIdx.x & 63;
  int c4 = lane * 4;
  int key = NKEY_P + NKEY_0 + row;
  int st = offs[key];
  int ln = lens[key];
  float bx = 0.f, by = 0.f, bz = 0.f, bw = 0.f;
  float dx = 0.f, dy = 0.f, dz = 0.f, dw = 0.f, den = 0.f;
  for (int i = 0; i < ln; ++i) {
    int pr = intA[st + i];
    int sr = intB[st + i - (NKEY_P + NKEY_0)];
    float w = fW[st + i - NKEY_P];
    short4 vb = *reinterpret_cast<const short4*>(&xm2[(size_t)pr * C0d + c4]);
    float4 vd = *reinterpret_cast<const float4*>(&x0[(size_t)sr * C0d + c4]);
    bx += bf2f(vb.x) * w; by += bf2f(vb.y) * w;
    bz += bf2f(vb.z) * w; bw += bf2f(vb.w) * w;
    dx += vd.x * w; dy += vd.y * w; dz += vd.z * w; dw += vd.w * w;
    den += w;
  }
  float inv = 1.f / (den + 1e-6f);
  float4 sk = *reinterpret_cast<const float4*>(&skip_w[c4]);
  float4 gg = *reinterpret_cast<const float4*>(&g[c4]);
  float4 bb = *reinterpret_cast<const float4*>(&beta[c4]);
  float4 mm = *reinterpret_cast<const float4*>(&mean[c4]);
  float4 vv = *reinterpret_cast<const float4*>(&var[c4]);
  float s0 = gg.x * rsqrtf(vv.x + 1e-5f), h0 = bb.x - mm.x * s0;
  float s1 = gg.y * rsqrtf(vv.y + 1e-5f), h1 = bb.y - mm.y * s1;
  float s2 = gg.z * rsqrtf(vv.z + 1e-5f), h2 = bb.z - mm.z * s2;
  float s3 = gg.w * rsqrtf(vv.w + 1e-5f), h3 = bb.w - mm.w * s3;
  short4 o;
  o.x = f2bf((dx * inv * sk.x + bx * inv) * s0 + h0);
  o.y = f2bf((dy * inv * sk.y + by * inv) * s1 + h1);
  o.z = f2bf((dz * inv * sk.z + bz * inv) * s2 + h2);
  o.w = f2bf((dw * inv * sk.w + bw * inv) * s3 + h3);
  *reinterpret_cast<short4*>(&xdf[(size_t)row * C0d + c4]) = o;
}

extern "C" void kernel_launch(void* const* d_in, const int* in_sizes, int n_in,
                              void* d_out, int out_size, void* d_ws, size_t ws_size,
                              hipStream_t stream) {
  const float* x0   = (const float*)d_in[0];
  const float* x1   = (const float*)d_in[1];
  const int*   idx0 = (const int*)d_in[2];
  const int*   idx1 = (const int*)d_in[3];
  const float* w0   = (const float*)d_in[4];
  const float* w1   = (const float*)d_in[5];
  const float* loc  = (const float*)d_in[6];
  const float* W01  = (const float*)d_in[7];
  const float* bn01_g = (const float*)d_in[8];
  const float* bn01_b = (const float*)d_in[9];
  const float* bn01_m = (const float*)d_in[10];
  const float* bn01_v = (const float*)d_in[11];
  const float* dw_w   = (const float*)d_in[12];
  const float* skip_w = (const float*)d_in[13];
  const float* bn1_g  = (const float*)d_in[14];
  const float* bn1_b  = (const float*)d_in[15];
  const float* bn1_m  = (const float*)d_in[16];
  const float* bn1_v  = (const float*)d_in[17];
  const float* conv_w = (const float*)d_in[18];
  const float* bn2_g  = (const float*)d_in[19];
  const float* bn2_b  = (const float*)d_in[20];
  const float* bn2_m  = (const float*)d_in[21];
  const float* bn2_v  = (const float*)d_in[22];

  float* out = (float*)d_out;
  float* num0 = out;                       // out0 [131072 x 256]
  float* out1 = out + 33554432;            // out1 [32768 x 512]

  // ---- workspace layout ----
  int*   counts = (int*)d_ws;              // NKEYS (-> offsets)
  int*   cursor = counts + NKEYS;          // NKEYS (-> lengths)
  int*   bsum   = cursor + NKEYS;          // 512
  int*   intA   = bsum + 512;              // 393216
  int*   intB   = intA + 393216;           // 131072
  float* fW     = (float*)(intB + 131072); // 262144
  float* dwT    = fW + 262144;             // 2560 (2304 used)
  short* xm2    = (short*)(dwT + 2560);    // 8,388,608 bf16
  short* srcb   = xm2 + 8388608;           // 8,388,608 bf16
  short* xdf    = srcb + 8388608;          // 8,388,608 bf16

  const int nbp = Bb * NPIX;               // 131072

  k_zero<<<(NZI4 + 255) / 256, 256, 0, stream>>>((int4*)d_ws);

  // CSR build
  k_count<<<nbp / 256, 256, 0, stream>>>(idx0, idx1, loc, counts);
  k_scan_block<<<SCAN_BLOCKS, 256, 0, stream>>>(counts, bsum);
  k_scan_top<<<1, 512, 0, stream>>>(bsum);
  k_scan_add<<<SCAN_BLOCKS, 256, 0, stream>>>(counts, bsum);
  k_fill<<<nbp / 256, 256, 0, stream>>>(idx0, idx1, w0, w1, loc, counts, cursor,
                                        intA, intB, fW);
  k_prepw<<<9, 256, 0, stream>>>(dw_w, dwT);

  // fused token2map + dw-conv -> xm2 (bf16)
  k_conv_v4<<<Bb * 4096 / 4, 256, 0, stream>>>(x0, counts, cursor, intA, dwT, xm2);

  // srcb(bf16) = bn01(x1 @ W01^T)   [32768 x 256]
  {
    dim3 grid(32768 / 128, 256 / 64);
    k_gemm_mfma<512, false, false, true><<<grid, 256, 0, stream>>>(
        (const void*)x1, W01, bn01_g, bn01_b, bn01_m, bn01_v, nullptr, (void*)srcb, 256);
  }

  // out0 = relu(x0 + gather(srcb))
  k_out0_v4<<<nbp / 4, 256, 0, stream>>>(srcb, x0, counts, cursor, intA, fW, num0);

  // xdf(bf16) = bn1(gather_d*skip + gather_b)
  k_out1_pre_v4<<<Bb * N1T / 4, 256, 0, stream>>>(xm2, x0, counts, cursor, intA, intB,
                                                  fW, skip_w, bn1_g, bn1_b, bn1_m, bn1_v,
                                                  xdf);

  // out1 = relu(x1 + bn2(xdf @ conv_w^T))  [32768 x 512]
  {
    dim3 grid(32768 / 128, 512 / 64);
    k_gemm_mfma<256, true, true, false><<<grid, 256, 0, stream>>>(
        (const void*)xdf, conv_w, bn2_g, bn2_b, bn2_m, bn2_v, x1, (void*)out1, 512);
  }
}